// Round 2
// baseline (6702.572 us; speedup 1.0000x reference)
//
#include <hip/hip_runtime.h>
#include <stdint.h>

// GGNN, aggregate-first formulation:
//   agg[n] = sum_t ( msg_W[t] @ s_t[n] ) + sum_t cnt_t[n]*msg_b[t]
//   where s_t[n] = sum_{e: dst=n, type=t} x[src[e]]
// Then fused GRU (no gi/gh materialization): x = GRU(agg, x).
// All fp32.

__device__ __forceinline__ float sigf(float a){ return 1.0f/(1.0f+__expf(-a)); }

__global__ void k_diag(float* out, int n, float v){
  int i = threadIdx.x; if(i<n) out[i] = v;
}

__global__ void k_embed(const int* __restrict__ xtype, const int* __restrict__ xtok,
                        const float* __restrict__ xsmall,
                        const float* __restrict__ temb, const float* __restrict__ kemb,
                        float* __restrict__ x, int N){
  int n = blockIdx.x; int j = threadIdx.x;
  if(n>=N) return;
  float v;
  if(j<32)       v = temb[xtype[n]*32 + j];
  else if(j<64)  v = kemb[xtok[n]*32 + (j-32)];
  else           v = xsmall[(size_t)n*64 + (j-64)];
  x[(size_t)n*128 + j] = v;
}

__global__ void k_hist3(const int* __restrict__ dst, const int* __restrict__ et,
                        int* __restrict__ deg3, int E){
  int e = blockIdx.x*blockDim.x + threadIdx.x;
  if(e<E) atomicAdd(&deg3[dst[e]*3 + et[e]], 1);
}

// inclusive scan per 1024-chunk (256 thr x 4 elems)
__global__ void k_scan1(const int* __restrict__ deg, int n, int* __restrict__ part, int* __restrict__ bsum){
  __shared__ int s[256];
  int t = threadIdx.x;
  int base = blockIdx.x*1024 + t*4;
  int v[4]; int sum=0;
  #pragma unroll
  for(int k=0;k<4;k++){ int i=base+k; int d=(i<n)?deg[i]:0; sum+=d; v[k]=sum; }
  s[t]=sum; __syncthreads();
  for(int off=1;off<256;off<<=1){
    int add = (t>=off)? s[t-off] : 0;
    __syncthreads();
    s[t]+=add;
    __syncthreads();
  }
  int excl = (t>0)? s[t-1] : 0;
  #pragma unroll
  for(int k=0;k<4;k++){ int i=base+k; if(i<n) part[i]=v[k]+excl; }
  if(t==255) bsum[blockIdx.x] = s[255];
}

__global__ void k_scan2(const int* __restrict__ bsum, int nb, int* __restrict__ carry){
  if(threadIdx.x==0 && blockIdx.x==0){
    int c=0;
    for(int b=0;b<nb;b++){ carry[b]=c; c+=bsum[b]; }
  }
}

__global__ void k_finalize(const int* __restrict__ part, const int* __restrict__ deg,
                           const int* __restrict__ carry, int n,
                           int* __restrict__ rowptr, int* __restrict__ cursor){
  int i = blockIdx.x*blockDim.x + threadIdx.x;
  if(i>=n) return;
  int incl = part[i] + carry[i>>10];
  rowptr[i+1] = incl;
  cursor[i] = incl - deg[i];
  if(i==0) rowptr[0]=0;
}

__global__ void k_fill3(const int* __restrict__ src, const int* __restrict__ dst,
                        const int* __restrict__ et, int* __restrict__ cursor,
                        int* __restrict__ pay, int E){
  int e = blockIdx.x*blockDim.x + threadIdx.x;
  if(e>=E) return;
  int pos = atomicAdd(&cursor[dst[e]*3 + et[e]], 1);
  pay[pos] = src[e];
}

// full: s[n, t*128+j] for all 3 types
__global__ void k_gather3(const float* __restrict__ x, const int* __restrict__ rp3,
                          const int* __restrict__ pay, float* __restrict__ s, int N){
  int n = blockIdx.x; if(n>=N) return;
  int j = threadIdx.x;
  int b = n*3;
  int e0=rp3[b], e1=rp3[b+1], e2=rp3[b+2], e3=rp3[b+3];
  float a0=0.f,a1=0.f,a2=0.f;
  for(int i=e0;i<e1;i++) a0 += x[(size_t)pay[i]*128 + j];
  for(int i=e1;i<e2;i++) a1 += x[(size_t)pay[i]*128 + j];
  for(int i=e2;i<e3;i++) a2 += x[(size_t)pay[i]*128 + j];
  size_t o=(size_t)n*384;
  s[o+j]=a0; s[o+128+j]=a1; s[o+256+j]=a2;
}

// lean: s_t only
__global__ void k_gather1(const float* __restrict__ x, const int* __restrict__ rp3,
                          const int* __restrict__ pay, float* __restrict__ st, int N, int t){
  int n = blockIdx.x; if(n>=N) return;
  int j = threadIdx.x;
  int b = n*3 + t;
  int e0=rp3[b], e1=rp3[b+1];
  float a=0.f;
  for(int i=e0;i<e1;i++) a += x[(size_t)pay[i]*128 + j];
  st[(size_t)n*128 + j] = a;
}

// C[M,128] (=/+=) A[M,K] @ B^T,  B[o,k] = Wflat[(k>>7)*16384 + o*128 + (k&127)]
// addbias: add typed-count bias sum_t cnt3[n,t]*msg_b[t,o]. accum: C += (no bias).
__global__ __launch_bounds__(256) void k_gemm_agg(
    const float* __restrict__ A, int M, int K,
    const float* __restrict__ Wflat, const float* __restrict__ msg_b,
    const int* __restrict__ cnt3, int addbias, int accum,
    float* __restrict__ C)
{
  __shared__ float As[16][132];
  __shared__ float Ws[16][132];
  int tid = threadIdx.x;
  int rowBase = blockIdx.y * 128;
  int ty = tid>>4, tx = tid&15;
  int mrow = ty*8, ncol = tx*8;
  float acc[8][8] = {};
  int r0 = tid>>2, c0 = (tid&3)*4;

  for(int k0=0;k0<K;k0+=16){
    int t = k0>>7, kloc = k0&127;
    #pragma unroll
    for(int p=0;p<2;p++){
      int r = r0+p*64; int gr = rowBase+r;
      float4 v = make_float4(0.f,0.f,0.f,0.f);
      if(gr<M) v = *(const float4*)(A + (size_t)gr*K + k0 + c0);
      As[c0+0][r]=v.x; As[c0+1][r]=v.y; As[c0+2][r]=v.z; As[c0+3][r]=v.w;
    }
    const float* Wc = Wflat + t*16384 + kloc;
    #pragma unroll
    for(int p=0;p<2;p++){
      int o = r0+p*64;
      float4 v = *(const float4*)(Wc + (size_t)o*128 + c0);
      Ws[c0+0][o]=v.x; Ws[c0+1][o]=v.y; Ws[c0+2][o]=v.z; Ws[c0+3][o]=v.w;
    }
    __syncthreads();
    #pragma unroll
    for(int kk=0;kk<16;kk++){
      float4 a0 = *(const float4*)&As[kk][mrow];
      float4 a1 = *(const float4*)&As[kk][mrow+4];
      float4 b0 = *(const float4*)&Ws[kk][ncol];
      float4 b1 = *(const float4*)&Ws[kk][ncol+4];
      float ar[8] = {a0.x,a0.y,a0.z,a0.w,a1.x,a1.y,a1.z,a1.w};
      float br[8] = {b0.x,b0.y,b0.z,b0.w,b1.x,b1.y,b1.z,b1.w};
      #pragma unroll
      for(int i=0;i<8;i++)
        #pragma unroll
        for(int j=0;j<8;j++)
          acc[i][j] += ar[i]*br[j];
    }
    __syncthreads();
  }
  #pragma unroll
  for(int i=0;i<8;i++){
    int gr = rowBase + mrow + i;
    if(gr >= M) continue;
    float* cp = C + (size_t)gr*128 + ncol;
    if(accum){
      #pragma unroll
      for(int j=0;j<8;j++) cp[j] += acc[i][j];
    } else {
      float b[8] = {};
      if(addbias){
        int q0=cnt3[gr*3], q1=cnt3[gr*3+1], q2=cnt3[gr*3+2];
        #pragma unroll
        for(int j=0;j<8;j++)
          b[j] = q0*msg_b[ncol+j] + q1*msg_b[128+ncol+j] + q2*msg_b[256+ncol+j];
      }
      #pragma unroll
      for(int j=0;j<8;j++) cp[j] = acc[i][j] + b[j];
    }
  }
}

// Fused GRU: per 32-row tile, stage agg & x in LDS; 6 phase sub-GEMMs (K=128 each)
// streaming W through LDS; pointwise GRU; x updated in place (row-local => safe).
#define GEMMK(At, Wb) do {                                                   \
    for(int k0=0;k0<128;k0+=16){                                             \
      int o_ = tid>>2; int cq_ = (tid&3)*4;                                  \
      _Pragma("unroll")                                                      \
      for(int p_=0;p_<2;p_++){                                               \
        int o2_ = o_ + p_*64;                                                \
        float4 v_ = *(const float4*)((Wb) + (size_t)o2_*128 + k0 + cq_);     \
        Ws[cq_+0][o2_]=v_.x; Ws[cq_+1][o2_]=v_.y;                            \
        Ws[cq_+2][o2_]=v_.z; Ws[cq_+3][o2_]=v_.w;                            \
      }                                                                      \
      __syncthreads();                                                       \
      _Pragma("unroll")                                                      \
      for(int kk=0;kk<16;kk++){                                              \
        float a0_ = At[k0+kk][mr];                                           \
        float a1_ = At[k0+kk][mr+1];                                         \
        float4 b0_ = *(const float4*)&Ws[kk][nc];                            \
        float4 b1_ = *(const float4*)&Ws[kk][nc+4];                          \
        float br_[8] = {b0_.x,b0_.y,b0_.z,b0_.w,b1_.x,b1_.y,b1_.z,b1_.w};    \
        _Pragma("unroll")                                                    \
        for(int j=0;j<8;j++){ accA[0][j]+=a0_*br_[j]; accA[1][j]+=a1_*br_[j]; } \
      }                                                                      \
      __syncthreads();                                                       \
    }                                                                        \
  } while(0)

#define ZEROACC() do { _Pragma("unroll") for(int i=0;i<2;i++) _Pragma("unroll") for(int j=0;j<8;j++) accA[i][j]=0.f; } while(0)

__global__ __launch_bounds__(256) void k_gru_fused(
    const float* __restrict__ agg, float* __restrict__ x,
    const float* __restrict__ W_ih, const float* __restrict__ W_hh,
    const float* __restrict__ b_ih, const float* __restrict__ b_hh, int M)
{
  __shared__ float Ag[128][36];
  __shared__ float Ax[128][36];
  __shared__ float Ws[16][132];
  int tid = threadIdx.x;
  int row0 = blockIdx.x * 32;
  {
    int r = tid>>3;             // 0..31
    int cb = (tid&7)*4;         // 0..28
    int gr = row0 + r;
    for(int c0=0;c0<128;c0+=32){
      int c = c0 + cb;
      float4 va = make_float4(0.f,0.f,0.f,0.f), vx = va;
      if(gr<M){
        va = *(const float4*)(agg + (size_t)gr*128 + c);
        vx = *(const float4*)(x   + (size_t)gr*128 + c);
      }
      Ag[c+0][r]=va.x; Ag[c+1][r]=va.y; Ag[c+2][r]=va.z; Ag[c+3][r]=va.w;
      Ax[c+0][r]=vx.x; Ax[c+1][r]=vx.y; Ax[c+2][r]=vx.z; Ax[c+3][r]=vx.w;
    }
  }
  __syncthreads();
  int ty = tid>>4, tx = tid&15;
  int mr = ty*2, nc = tx*8;
  float accA[2][8];
  float rr[2][8];

  // r = sigmoid(agg@Wih_r^T + x@Whh_r^T + b)
  ZEROACC();
  GEMMK(Ag, W_ih);
  GEMMK(Ax, W_hh);
  #pragma unroll
  for(int i=0;i<2;i++)
    #pragma unroll
    for(int j=0;j<8;j++) rr[i][j] = sigf(accA[i][j] + b_ih[nc+j] + b_hh[nc+j]);
  // rh = r * (x@Whh_n^T + b_hh_n)
  ZEROACC();
  GEMMK(Ax, (W_hh + 256*128));
  #pragma unroll
  for(int i=0;i<2;i++)
    #pragma unroll
    for(int j=0;j<8;j++) rr[i][j] = rr[i][j] * (accA[i][j] + b_hh[256+nc+j]);
  // n = tanh(agg@Wih_n^T + b_ih_n + rh)
  ZEROACC();
  GEMMK(Ag, (W_ih + 256*128));
  #pragma unroll
  for(int i=0;i<2;i++)
    #pragma unroll
    for(int j=0;j<8;j++) rr[i][j] = tanhf(accA[i][j] + b_ih[256+nc+j] + rr[i][j]);
  // z, update
  ZEROACC();
  GEMMK(Ag, (W_ih + 128*128));
  GEMMK(Ax, (W_hh + 128*128));
  #pragma unroll
  for(int i=0;i<2;i++){
    int gr = row0 + mr + i;
    if(gr < M){
      float xv[8];
      #pragma unroll
      for(int j=0;j<8;j++){
        float z = sigf(accA[i][j] + b_ih[128+nc+j] + b_hh[128+nc+j]);
        float xo = Ax[nc+j][mr+i];
        xv[j] = (1.f - z)*rr[i][j] + z*xo;
      }
      float* xp = x + (size_t)gr*128 + nc;
      *(float4*)(xp)   = make_float4(xv[0],xv[1],xv[2],xv[3]);
      *(float4*)(xp+4) = make_float4(xv[4],xv[5],xv[6],xv[7]);
    }
  }
}

__global__ void k_pool(const float* __restrict__ x, const int* __restrict__ batch,
                       float* __restrict__ pooled, float* __restrict__ cnt, int N){
  int idx = blockIdx.x*blockDim.x + threadIdx.x;
  if(idx >= N*128) return;
  int n = idx>>7, j = idx&127;
  int g = batch[n];
  atomicAdd(&pooled[g*128+j], x[idx]);
  if(j==0) atomicAdd(&cnt[g], 1.0f);
}

__global__ void k_head(const float* __restrict__ pooled, const float* __restrict__ cnt,
                       const float* __restrict__ W1, const float* __restrict__ b1,
                       const float* __restrict__ W2, const float* __restrict__ b2,
                       float* __restrict__ out){
  int g = blockIdx.x; int j = threadIdx.x;
  __shared__ float p[128];
  __shared__ float red[128];
  float c = cnt[g]; c = c > 1.f ? c : 1.f;
  p[j] = pooled[g*128+j] / c;
  __syncthreads();
  float acc = b1[j];
  #pragma unroll 4
  for(int i=0;i<128;i++) acc += W1[j*128+i]*p[i];
  float v = (acc>0.f?acc:0.f) * W2[j];
  red[j] = v; __syncthreads();
  for(int s=64;s>0;s>>=1){ if(j<s) red[j]+=red[j+s]; __syncthreads(); }
  if(j==0) out[g] = red[0] + b2[0];
}

extern "C" void kernel_launch(void* const* d_in, const int* in_sizes, int n_in,
                              void* d_out, int out_size, void* d_ws, size_t ws_size,
                              hipStream_t stream){
  const int*   x_type    = (const int*)d_in[0];
  const int*   x_tok     = (const int*)d_in[1];
  const float* x_small   = (const float*)d_in[2];
  const int*   edge_index= (const int*)d_in[3];
  const int*   edge_type = (const int*)d_in[4];
  const int*   batch     = (const int*)d_in[5];
  const float* type_emb  = (const float*)d_in[6];
  const float* tok_emb   = (const float*)d_in[7];
  const float* msg_W     = (const float*)d_in[8];
  const float* msg_b     = (const float*)d_in[9];
  const float* W_ih      = (const float*)d_in[10];
  const float* W_hh      = (const float*)d_in[11];
  const float* b_ih      = (const float*)d_in[12];
  const float* b_hh      = (const float*)d_in[13];
  const float* pW1       = (const float*)d_in[14];
  const float* pb1       = (const float*)d_in[15];
  const float* pW2       = (const float*)d_in[16];
  const float* pb2       = (const float*)d_in[17];
  float* out = (float*)d_out;

  int N = in_sizes[0];
  int E = in_sizes[3]/2;
  const int* src = edge_index;
  const int* dst = edge_index + E;
  int n3 = 3*N;
  int nch = (n3+1023)/1024;

  char* w = (char*)d_ws;
  size_t off = 0;
  auto alloc = [&](size_t bytes)->char*{ char* p = w + off; off += (bytes + 511) & ~511ull; return p; };
  float* x      = (float*)alloc((size_t)N*128*4);
  float* agg    = (float*)alloc((size_t)N*128*4);
  int*   deg3   = (int*)alloc((size_t)n3*4);
  int*   part   = (int*)alloc((size_t)n3*4);
  int*   rp3    = (int*)alloc((size_t)(n3+1)*4);
  int*   cursor = (int*)alloc((size_t)n3*4);
  int*   pay    = (int*)alloc((size_t)E*4);
  int*   bsum   = (int*)alloc((size_t)nch*4);
  int*   carry  = (int*)alloc((size_t)nch*4);
  float* pooled = (float*)alloc(64*128*4);
  float* cntg   = (float*)alloc(64*4);
  float* sbuf   = (float*)(w + off);   // tail region: s (N*384) or s_t (N*128)
  size_t lean_need = off + (size_t)N*128*4;
  size_t full_need = off + (size_t)N*384*4;
  int mode = (ws_size >= full_need) ? 2 : (ws_size >= lean_need) ? 1 : 0;
  if(mode == 0){
    k_diag<<<1,64,0,stream>>>(out, out_size, 1.0e6f + (float)(ws_size>>20));
    return;
  }

  const int tb = 256;
  hipMemsetAsync(deg3, 0, (size_t)n3*4, stream);
  k_hist3   <<<(E+tb-1)/tb, tb, 0, stream>>>(dst, edge_type, deg3, E);
  k_scan1   <<<nch, 256, 0, stream>>>(deg3, n3, part, bsum);
  k_scan2   <<<1, 64, 0, stream>>>(bsum, nch, carry);
  k_finalize<<<(n3+tb-1)/tb, tb, 0, stream>>>(part, deg3, carry, n3, rp3, cursor);
  k_fill3   <<<(E+tb-1)/tb, tb, 0, stream>>>(src, dst, edge_type, cursor, pay, E);
  k_embed   <<<N, 128, 0, stream>>>(x_type, x_tok, x_small, type_emb, tok_emb, x, N);

  int mt = (N+127)/128;
  for(int it=0; it<8; it++){
    if(mode == 2){
      k_gather3 <<<N, 128, 0, stream>>>(x, rp3, pay, sbuf, N);
      k_gemm_agg<<<dim3(1,mt), 256, 0, stream>>>(sbuf, N, 384, msg_W, msg_b, deg3, 1, 0, agg);
    } else {
      for(int t=0;t<3;t++){
        k_gather1 <<<N, 128, 0, stream>>>(x, rp3, pay, sbuf, N, t);
        k_gemm_agg<<<dim3(1,mt), 256, 0, stream>>>(sbuf, N, 128, msg_W + t*16384, msg_b, deg3,
                                                   (t==0)?1:0, (t==0)?0:1, agg);
      }
    }
    k_gru_fused<<<(N+31)/32, 256, 0, stream>>>(agg, x, W_ih, W_hh, b_ih, b_hh, N);
  }
  hipMemsetAsync(pooled, 0, 64*128*4, stream);
  hipMemsetAsync(cntg, 0, 64*4, stream);
  k_pool<<<(N*128+tb-1)/tb, tb, 0, stream>>>(x, batch, pooled, cntg, N);
  k_head<<<64, 128, 0, stream>>>(pooled, cntg, pW1, pb1, pW2, pb2, out);
}

// Round 3
// 2808.610 us; speedup vs baseline: 2.3864x; 2.3864x over previous
//
#include <hip/hip_runtime.h>
#include <stdint.h>

// GGNN, aggregate-first + MFMA bf16 with hi/lo weight split.
//   s_t[n] = sum_{e: dst=n, type=t} x[src[e]]           (gather, fp32->bf16)
//   agg    = s @ msgWcat^T + typed bias                  (MFMA, K=384)
//   gi     = agg @ W_ih^T + b_ih   (overwrites s buf)    (MFMA, K=128)
//   gh     = x @ W_hh^T + b_hh                           (MFMA, K=128, A fp32->bf16 in staging)
//   x      = GRU(gi, gh, x)  fp32 master state
// Weights split W = hi + lo (both bf16): acc += A*hi + A*lo  => ~16-bit weight mantissa.

typedef __bf16 bf16;
typedef __bf16 v8bf  __attribute__((ext_vector_type(8)));
typedef __bf16 v2bf  __attribute__((ext_vector_type(2)));
typedef float  v16f  __attribute__((ext_vector_type(16)));

__device__ __forceinline__ float sigf(float a){ return 1.0f/(1.0f+__expf(-a)); }

__global__ void k_diag(float* out, int n, float v){
  int i = threadIdx.x; if(i<n) out[i] = v;
}

__global__ void k_embed(const int* __restrict__ xtype, const int* __restrict__ xtok,
                        const float* __restrict__ xsmall,
                        const float* __restrict__ temb, const float* __restrict__ kemb,
                        float* __restrict__ x, int N){
  int n = blockIdx.x; int j = threadIdx.x;
  if(n>=N) return;
  float v;
  if(j<32)       v = temb[xtype[n]*32 + j];
  else if(j<64)  v = kemb[xtok[n]*32 + (j-32)];
  else           v = xsmall[(size_t)n*64 + (j-64)];
  x[(size_t)n*128 + j] = v;
}

// weight prep: build Whi/Wlo, layout:
//   [0      , 49152) : msg cat  [o=128][k=384], k = t*128 + kk
//   [49152  , 98304) : W_ih     [o=384][k=128]
//   [98304  ,147456) : W_hh     [o=384][k=128]
__global__ void k_wprep(const float* __restrict__ msg_W, const float* __restrict__ W_ih,
                        const float* __restrict__ W_hh,
                        bf16* __restrict__ Whi, bf16* __restrict__ Wlo){
  int i = blockIdx.x*256 + threadIdx.x;
  if(i >= 147456) return;
  float w;
  if(i < 49152){
    int o = i/384, k = i%384;
    w = msg_W[(size_t)(k>>7)*16384 + o*128 + (k&127)];
  } else if(i < 98304){
    w = W_ih[i-49152];
  } else {
    w = W_hh[i-98304];
  }
  bf16 h = (bf16)w;
  float lo = w - (float)h;
  Whi[i] = h; Wlo[i] = (bf16)lo;
}

__global__ void k_hist3(const int* __restrict__ dst, const int* __restrict__ et,
                        int* __restrict__ deg3, int E){
  int e = blockIdx.x*blockDim.x + threadIdx.x;
  if(e<E) atomicAdd(&deg3[dst[e]*3 + et[e]], 1);
}

__global__ void k_scan1(const int* __restrict__ deg, int n, int* __restrict__ part, int* __restrict__ bsum){
  __shared__ int s[256];
  int t = threadIdx.x;
  int base = blockIdx.x*1024 + t*4;
  int v[4]; int sum=0;
  #pragma unroll
  for(int k=0;k<4;k++){ int i=base+k; int d=(i<n)?deg[i]:0; sum+=d; v[k]=sum; }
  s[t]=sum; __syncthreads();
  for(int off=1;off<256;off<<=1){
    int add = (t>=off)? s[t-off] : 0;
    __syncthreads();
    s[t]+=add;
    __syncthreads();
  }
  int excl = (t>0)? s[t-1] : 0;
  #pragma unroll
  for(int k=0;k<4;k++){ int i=base+k; if(i<n) part[i]=v[k]+excl; }
  if(t==255) bsum[blockIdx.x] = s[255];
}

__global__ void k_scan2(const int* __restrict__ bsum, int nb, int* __restrict__ carry){
  if(threadIdx.x==0 && blockIdx.x==0){
    int c=0;
    for(int b=0;b<nb;b++){ carry[b]=c; c+=bsum[b]; }
  }
}

__global__ void k_finalize(const int* __restrict__ part, const int* __restrict__ deg,
                           const int* __restrict__ carry, int n,
                           int* __restrict__ rowptr, int* __restrict__ cursor){
  int i = blockIdx.x*blockDim.x + threadIdx.x;
  if(i>=n) return;
  int incl = part[i] + carry[i>>10];
  rowptr[i+1] = incl;
  cursor[i] = incl - deg[i];
  if(i==0) rowptr[0]=0;
}

__global__ void k_fill3(const int* __restrict__ src, const int* __restrict__ dst,
                        const int* __restrict__ et, int* __restrict__ cursor,
                        int* __restrict__ pay, int E){
  int e = blockIdx.x*blockDim.x + threadIdx.x;
  if(e>=E) return;
  int pos = atomicAdd(&cursor[dst[e]*3 + et[e]], 1);
  pay[pos] = src[e];
}

// gather: s[n, t*128 + c] = sum over typed in-edges of x[src]; 4 nodes/block, 2 cols/lane
__global__ void k_gather3(const float* __restrict__ x, const int* __restrict__ rp3,
                          const int* __restrict__ pay, bf16* __restrict__ s, int N){
  int n = blockIdx.x*4 + (threadIdx.x>>6);
  if(n>=N) return;
  int lane = threadIdx.x & 63;
  int c = lane*2;
  int b = n*3;
  int e0=rp3[b], e1=rp3[b+1], e2=rp3[b+2], e3=rp3[b+3];
  float a0=0.f,b0=0.f,a1=0.f,b1=0.f,a2=0.f,b2=0.f;
  for(int i=e0;i<e1;i++){ float2 v = *(const float2*)&x[(size_t)pay[i]*128 + c]; a0+=v.x; b0+=v.y; }
  for(int i=e1;i<e2;i++){ float2 v = *(const float2*)&x[(size_t)pay[i]*128 + c]; a1+=v.x; b1+=v.y; }
  for(int i=e2;i<e3;i++){ float2 v = *(const float2*)&x[(size_t)pay[i]*128 + c]; a2+=v.x; b2+=v.y; }
  size_t o = (size_t)n*384 + c;
  v2bf t;
  t[0]=(bf16)a0; t[1]=(bf16)b0; *(v2bf*)&s[o]       = t;
  t[0]=(bf16)a1; t[1]=(bf16)b1; *(v2bf*)&s[o+128]   = t;
  t[0]=(bf16)a2; t[1]=(bf16)b2; *(v2bf*)&s[o+256]   = t;
}

// MFMA GEMM: C[M, O-block] = A[M,K] @ W^T (+bias), W=[O][K] row-major split hi/lo bf16.
// Block tile 128x128, wave tile 64x64 (2x2 of 32x32x16 bf16), BK=64.
// biasmode 0: bias[n,o] = sum_t deg3[n,t]*msg_b[t,o]; biasmode 1: bias[o] = biasv[colg].
// AFP32: A is fp32 (converted during staging), else bf16.
#define LDSTR 72   // padded K-stride (bf16 elems); 144B rows, 16B-aligned, max 4-way bank alias
template<int AFP32>
__global__ __launch_bounds__(256) void k_gemm_mfma(
    const void* __restrict__ Aptr, int lda, int M, int K,
    const bf16* __restrict__ Bhi, const bf16* __restrict__ Blo, int ldb,
    const float* __restrict__ biasv,
    const int* __restrict__ deg3, const float* __restrict__ msg_b, int biasmode,
    bf16* __restrict__ C, int ldc)
{
  __shared__ bf16 As[128*LDSTR];
  __shared__ bf16 Bh[128*LDSTR];
  __shared__ bf16 Bl[128*LDSTR];
  int tid = threadIdx.x;
  int colBase = blockIdx.x * 128;
  int rowBase = blockIdx.y * 128;
  int lane = tid & 63, wave = tid >> 6;
  int wm = (wave&1)*64, wn = (wave>>1)*64;
  int lrow = lane & 31, lk8 = (lane>>5)*8;

  v16f acc[2][2] = {};

  for(int k0=0; k0<K; k0+=64){
    #pragma unroll
    for(int p=0;p<4;p++){
      int ch = tid + p*256;            // 0..1023
      int row = ch>>3;
      int c8 = (ch&7)*8;
      int gr = rowBase + row; if(gr >= M) gr = M-1;   // clamp: rows>=M computed but never stored
      if(AFP32){
        const float* ap = (const float*)Aptr + (size_t)gr*lda + k0 + c8;
        float4 f0 = *(const float4*)ap;
        float4 f1 = *(const float4*)(ap+4);
        v8bf t;
        t[0]=(bf16)f0.x; t[1]=(bf16)f0.y; t[2]=(bf16)f0.z; t[3]=(bf16)f0.w;
        t[4]=(bf16)f1.x; t[5]=(bf16)f1.y; t[6]=(bf16)f1.z; t[7]=(bf16)f1.w;
        *(v8bf*)&As[row*LDSTR + c8] = t;
      } else {
        const bf16* ap = (const bf16*)Aptr + (size_t)gr*lda + k0 + c8;
        *(v8bf*)&As[row*LDSTR + c8] = *(const v8bf*)ap;
      }
      size_t bo = (size_t)(colBase + row)*ldb + k0 + c8;
      *(v8bf*)&Bh[row*LDSTR + c8] = *(const v8bf*)(Bhi + bo);
      *(v8bf*)&Bl[row*LDSTR + c8] = *(const v8bf*)(Blo + bo);
    }
    __syncthreads();
    #pragma unroll
    for(int ks=0;ks<4;ks++){
      int kb = ks*16 + lk8;
      v8bf a0  = *(const v8bf*)&As[(wm     + lrow)*LDSTR + kb];
      v8bf a1  = *(const v8bf*)&As[(wm+32  + lrow)*LDSTR + kb];
      v8bf bh0 = *(const v8bf*)&Bh[(wn     + lrow)*LDSTR + kb];
      v8bf bh1 = *(const v8bf*)&Bh[(wn+32  + lrow)*LDSTR + kb];
      v8bf bl0 = *(const v8bf*)&Bl[(wn     + lrow)*LDSTR + kb];
      v8bf bl1 = *(const v8bf*)&Bl[(wn+32  + lrow)*LDSTR + kb];
      acc[0][0] = __builtin_amdgcn_mfma_f32_32x32x16_bf16(a0, bh0, acc[0][0], 0,0,0);
      acc[0][1] = __builtin_amdgcn_mfma_f32_32x32x16_bf16(a0, bh1, acc[0][1], 0,0,0);
      acc[1][0] = __builtin_amdgcn_mfma_f32_32x32x16_bf16(a1, bh0, acc[1][0], 0,0,0);
      acc[1][1] = __builtin_amdgcn_mfma_f32_32x32x16_bf16(a1, bh1, acc[1][1], 0,0,0);
      acc[0][0] = __builtin_amdgcn_mfma_f32_32x32x16_bf16(a0, bl0, acc[0][0], 0,0,0);
      acc[0][1] = __builtin_amdgcn_mfma_f32_32x32x16_bf16(a0, bl1, acc[0][1], 0,0,0);
      acc[1][0] = __builtin_amdgcn_mfma_f32_32x32x16_bf16(a1, bl0, acc[1][0], 0,0,0);
      acc[1][1] = __builtin_amdgcn_mfma_f32_32x32x16_bf16(a1, bl1, acc[1][1], 0,0,0);
    }
    __syncthreads();
  }

  // epilogue: C/D layout (32x32): col = lane&31, row = (r&3) + 8*(r>>2) + 4*(lane>>5)
  int rowq4 = 4*(lane>>5);
  #pragma unroll
  for(int mt=0;mt<2;mt++){
    #pragma unroll
    for(int nt=0;nt<2;nt++){
      int colg = colBase + wn + nt*32 + lrow;
      float bb=0.f, mb0=0.f, mb1=0.f, mb2=0.f;
      if(biasmode==1){ bb = biasv[colg]; }
      else { int cl = wn + nt*32 + lrow; mb0 = msg_b[cl]; mb1 = msg_b[128+cl]; mb2 = msg_b[256+cl]; }
      #pragma unroll
      for(int r=0;r<16;r++){
        int gr = rowBase + wm + mt*32 + (r&3) + 8*(r>>2) + rowq4;
        if(gr >= M) continue;
        float v = acc[mt][nt][r];
        if(biasmode==0){
          const int* dq = &deg3[gr*3];
          v += dq[0]*mb0 + dq[1]*mb1 + dq[2]*mb2;
        } else v += bb;
        C[(size_t)gr*ldc + colg] = (bf16)v;
      }
    }
  }
}

// GRU pointwise, fp32 master state; gi/gh bf16, ld=384
__global__ void k_gru(const bf16* __restrict__ gi, const bf16* __restrict__ gh,
                      float* __restrict__ x, int N){
  int idx = blockIdx.x*blockDim.x + threadIdx.x;
  if(idx >= N*128) return;
  int n = idx>>7, j = idx&127;
  const bf16* gin = gi + (size_t)n*384;
  const bf16* ghn = gh + (size_t)n*384;
  float ir=(float)gin[j], iz=(float)gin[128+j], in_=(float)gin[256+j];
  float hr=(float)ghn[j], hz=(float)ghn[128+j], hn=(float)ghn[256+j];
  float r = sigf(ir+hr);
  float z = sigf(iz+hz);
  float nn = tanhf(in_ + r*hn);
  x[idx] = (1.f - z)*nn + z*x[idx];
}

__device__ __forceinline__ int lb_batch(const int* __restrict__ batch, int N, int g){
  int lo=0, hi=N;
  while(lo<hi){ int mid=(lo+hi)>>1; if(batch[mid]<g) lo=mid+1; else hi=mid; }
  return lo;
}

// pooled sums via sorted-batch range scan; 4 row-slices per graph, 32k atomics total
__global__ void k_pool2(const float* __restrict__ x, const int* __restrict__ batch,
                        float* __restrict__ pooled, int N){
  int g = blockIdx.x, slice = blockIdx.y;
  int j = threadIdx.x;
  int lo = lb_batch(batch,N,g), hi = lb_batch(batch,N,g+1);
  float acc = 0.f;
  for(int r=lo+slice; r<hi; r+=4) acc += x[(size_t)r*128 + j];
  atomicAdd(&pooled[g*128+j], acc);
}

__global__ void k_head(const float* __restrict__ pooled, const int* __restrict__ batch, int N,
                       const float* __restrict__ W1, const float* __restrict__ b1,
                       const float* __restrict__ W2, const float* __restrict__ b2,
                       float* __restrict__ out){
  int g = blockIdx.x; int j = threadIdx.x;
  __shared__ float p[128];
  __shared__ float red[128];
  int lo = lb_batch(batch,N,g), hi = lb_batch(batch,N,g+1);
  float c = (float)(hi-lo); if(c < 1.f) c = 1.f;
  p[j] = pooled[g*128+j] / c;
  __syncthreads();
  float acc = b1[j];
  #pragma unroll 4
  for(int i=0;i<128;i++) acc += W1[j*128+i]*p[i];
  float v = (acc>0.f?acc:0.f) * W2[j];
  red[j] = v; __syncthreads();
  for(int s=64;s>0;s>>=1){ if(j<s) red[j]+=red[j+s]; __syncthreads(); }
  if(j==0) out[g] = red[0] + b2[0];
}

extern "C" void kernel_launch(void* const* d_in, const int* in_sizes, int n_in,
                              void* d_out, int out_size, void* d_ws, size_t ws_size,
                              hipStream_t stream){
  const int*   x_type    = (const int*)d_in[0];
  const int*   x_tok     = (const int*)d_in[1];
  const float* x_small   = (const float*)d_in[2];
  const int*   edge_index= (const int*)d_in[3];
  const int*   edge_type = (const int*)d_in[4];
  const int*   batch     = (const int*)d_in[5];
  const float* type_emb  = (const float*)d_in[6];
  const float* tok_emb   = (const float*)d_in[7];
  const float* msg_W     = (const float*)d_in[8];
  const float* msg_b     = (const float*)d_in[9];
  const float* W_ih      = (const float*)d_in[10];
  const float* W_hh      = (const float*)d_in[11];
  const float* b_ih      = (const float*)d_in[12];
  const float* b_hh      = (const float*)d_in[13];
  const float* pW1       = (const float*)d_in[14];
  const float* pb1       = (const float*)d_in[15];
  const float* pW2       = (const float*)d_in[16];
  const float* pb2       = (const float*)d_in[17];
  float* out = (float*)d_out;

  int N = in_sizes[0];
  int E = in_sizes[3]/2;
  const int* src = edge_index;
  const int* dst = edge_index + E;
  int n3 = 3*N;
  int nch = (n3+1023)/1024;

  char* w = (char*)d_ws;
  size_t off = 0;
  auto alloc = [&](size_t bytes)->char*{ char* p = w + off; off += (bytes + 511) & ~511ull; return p; };
  float* x      = (float*)alloc((size_t)N*128*4);     // fp32 master state
  bf16*  s      = (bf16*)alloc((size_t)N*384*2);      // s, then gi
  bf16*  gh     = (bf16*)alloc((size_t)N*384*2);
  bf16*  agg    = (bf16*)alloc((size_t)N*128*2);
  int*   deg3   = (int*)alloc((size_t)n3*4);
  int*   part   = (int*)alloc((size_t)n3*4);
  int*   rp3    = (int*)alloc((size_t)(n3+1)*4);
  int*   cursor = (int*)alloc((size_t)n3*4);
  int*   pay    = (int*)alloc((size_t)E*4);
  int*   bsum   = (int*)alloc((size_t)nch*4);
  int*   carry  = (int*)alloc((size_t)nch*4);
  bf16*  Whi    = (bf16*)alloc((size_t)147456*2);
  bf16*  Wlo    = (bf16*)alloc((size_t)147456*2);
  float* pooled = (float*)alloc(64*128*4);
  if(off > ws_size){
    k_diag<<<1,64,0,stream>>>(out, out_size, 1.0e6f + (float)(ws_size>>20));
    return;
  }

  const int tb = 256;
  hipMemsetAsync(deg3, 0, (size_t)n3*4, stream);
  k_wprep   <<<576, 256, 0, stream>>>(msg_W, W_ih, W_hh, Whi, Wlo);
  k_hist3   <<<(E+tb-1)/tb, tb, 0, stream>>>(dst, edge_type, deg3, E);
  k_scan1   <<<nch, 256, 0, stream>>>(deg3, n3, part, bsum);
  k_scan2   <<<1, 64, 0, stream>>>(bsum, nch, carry);
  k_finalize<<<(n3+tb-1)/tb, tb, 0, stream>>>(part, deg3, carry, n3, rp3, cursor);
  k_fill3   <<<(E+tb-1)/tb, tb, 0, stream>>>(src, dst, edge_type, cursor, pay, E);
  k_embed   <<<N, 128, 0, stream>>>(x_type, x_tok, x_small, type_emb, tok_emb, x, N);

  int mt = (N+127)/128;
  for(int it=0; it<8; it++){
    k_gather3<<<(N+3)/4, 256, 0, stream>>>(x, rp3, pay, s, N);
    // agg = s @ msgWcat^T + typed bias
    k_gemm_mfma<0><<<dim3(1,mt), 256, 0, stream>>>(s, 384, N, 384, Whi, Wlo, 384,
                                                   nullptr, deg3, msg_b, 0, agg, 128);
    // gh = x @ W_hh^T + b_hh   (A fp32)
    k_gemm_mfma<1><<<dim3(3,mt), 256, 0, stream>>>(x, 128, N, 128, Whi+98304, Wlo+98304, 128,
                                                   b_hh, nullptr, nullptr, 1, gh, 384);
    // gi = agg @ W_ih^T + b_ih  -> overwrites s
    k_gemm_mfma<0><<<dim3(3,mt), 256, 0, stream>>>(agg, 128, N, 128, Whi+49152, Wlo+49152, 128,
                                                   b_ih, nullptr, nullptr, 1, s, 384);
    k_gru<<<(N*128+tb-1)/tb, tb, 0, stream>>>(s, gh, x, N);
  }
  hipMemsetAsync(pooled, 0, 64*128*4, stream);
  k_pool2<<<dim3(64,4), 128, 0, stream>>>(x, batch, pooled, N);
  k_head <<<64, 128, 0, stream>>>(pooled, batch, N, pW1, pb1, pW2, pb2, out);
}